// Round 3
// baseline (479.294 us; speedup 1.0000x reference)
//
#include <hip/hip_runtime.h>
#include <hip/hip_bf16.h>

#define B_ 8
#define C_ 256
#define N_ 4096
#define S_ 64
#define LOG2E 1.4426950408889634f

typedef __attribute__((ext_vector_type(8))) short short8;
typedef __attribute__((ext_vector_type(4))) short short4v;
typedef __attribute__((ext_vector_type(4))) float f32x4;

__device__ __forceinline__ short f2b(float f) {
  unsigned u = __float_as_uint(f);
  unsigned r = (u + 0x7FFFu + ((u >> 16) & 1u)) >> 16;
  return (short)(r & 0xFFFFu);
}

// pack two f32 -> two bf16 in one instr (lo -> [15:0], hi -> [31:16])
__device__ __forceinline__ int cvtpk(float lo, float hi) {
  int r;
  asm("v_cvt_pk_bf16_f32 %0, %1, %2" : "=v"(r) : "v"(lo), "v"(hi));
  return r;
}

// K0: transpose+convert x (f32 [b][c][n]) -> xt (bf16 [b][n][c])
// 1D grid 2048, b = bid&7 (XCD-clustered so xt[b] lands in XCD-b's L2)
__global__ __launch_bounds__(256) void k0_transpose(const float* __restrict__ x,
                                                    short* __restrict__ xt) {
  __shared__ float tile[64][65];
  int bid = blockIdx.x;
  int b = bid & 7;
  int rest = bid >> 3;            // 256 = 4 c-blocks x 64 n-blocks
  int c0 = (rest & 3) * 64, n0 = (rest >> 2) * 64;
  int tn = threadIdx.x & 63, tc = threadIdx.x >> 6;
  const float* xb = x + ((size_t)b * C_ + c0) * N_ + n0;
#pragma unroll
  for (int i = 0; i < 16; i++) {
    int c = tc * 16 + i;
    tile[c][tn] = xb[(size_t)c * N_ + tn];
  }
  __syncthreads();
  short* xtb = xt + ((size_t)b * N_ + n0) * C_ + c0;
#pragma unroll
  for (int i = 0; i < 16; i++) {
    int n = tc * 16 + i;
    xtb[(size_t)n * C_ + tn] = f2b(tile[tn][n]);
  }
}

// KW: one-shot f32->bf16 convert of W_v and W_t (65536 elems each)
__global__ __launch_bounds__(256) void kw_conv(const float* __restrict__ Wv,
    const float* __restrict__ Wt, short* __restrict__ Wvb, short* __restrict__ Wtb) {
  int t = blockIdx.x * 256 + threadIdx.x;           // 16384 threads
  const float* src = (t < 8192) ? Wv : Wt;
  short* dst = (t < 8192) ? Wvb : Wtb;
  int i = (t & 8191) * 8;
  short8 o;
#pragma unroll
  for (int j = 0; j < 8; j++) o[j] = f2b(src[i + j]);
  *(short8*)(dst + i) = o;
}

// K1: xqk = W_qk*x (f32); Qt bf16 [b][n][s] PRE-SCALED by log2(e); Kt = softmax(k2c) bf16.
// 1D grid 512, b = bid&7.
__global__ __launch_bounds__(256) void k1_qk(const float* __restrict__ x,
    const float* __restrict__ Wqk, const float* __restrict__ Wk2c,
    const int* __restrict__ idx, short* __restrict__ Qt, short* __restrict__ Kt) {
  int bid = blockIdx.x;
  int b = bid & 7, n0 = (bid >> 3) * 64;
  int tn = threadIdx.x;
  int sg = __builtin_amdgcn_readfirstlane(threadIdx.y);
  const float* xb = x + (size_t)b * C_ * N_ + n0 + tn;
  float acc[16];
#pragma unroll
  for (int i = 0; i < 16; i++) acc[i] = 0.f;
  for (int c = 0; c < C_; c += 4) {
    float x0 = xb[(size_t)c * N_];
    float x1 = xb[(size_t)(c + 1) * N_];
    float x2 = xb[(size_t)(c + 2) * N_];
    float x3 = xb[(size_t)(c + 3) * N_];
#pragma unroll
    for (int i = 0; i < 16; i++) {
      const float* wr = Wqk + (sg * 16 + i) * C_ + c;
      acc[i] += wr[0] * x0 + wr[1] * x1 + wr[2] * x2 + wr[3] * x3;
    }
  }
  __shared__ float q_lds[64][65];
  __shared__ float red[4][64];
#pragma unroll
  for (int i = 0; i < 16; i++) q_lds[sg * 16 + i][tn] = acc[i];
  {
    short* qrow = Qt + ((size_t)b * N_ + n0 + tn) * S_ + sg * 16;
#pragma unroll
    for (int i = 0; i < 16; i++) qrow[i] = f2b(acc[i] * LOG2E);
  }
  __syncthreads();
  float acc2[16];
#pragma unroll
  for (int i = 0; i < 16; i++) acc2[i] = 0.f;
  for (int h = 0; h < 64; h += 4) {
    float q0 = q_lds[h][tn], q1 = q_lds[h + 1][tn];
    float q2 = q_lds[h + 2][tn], q3 = q_lds[h + 3][tn];
#pragma unroll
    for (int i = 0; i < 16; i++) {
      const float* wr = Wk2c + (sg * 16 + i) * 128 + h;
      acc2[i] += wr[0] * q0 + wr[1] * q1 + wr[2] * q2 + wr[3] * q3;
    }
  }
  for (int h = 0; h < 64; h += 4) {
    float g0 = xb[(size_t)idx[h] * N_];
    float g1 = xb[(size_t)idx[h + 1] * N_];
    float g2 = xb[(size_t)idx[h + 2] * N_];
    float g3 = xb[(size_t)idx[h + 3] * N_];
#pragma unroll
    for (int i = 0; i < 16; i++) {
      const float* wr = Wk2c + (sg * 16 + i) * 128 + 64 + h;
      acc2[i] += wr[0] * g0 + wr[1] * g1 + wr[2] * g2 + wr[3] * g3;
    }
  }
  float pm = acc2[0];
#pragma unroll
  for (int i = 1; i < 16; i++) pm = fmaxf(pm, acc2[i]);
  red[sg][tn] = pm;
  __syncthreads();
  float mx = fmaxf(fmaxf(red[0][tn], red[1][tn]), fmaxf(red[2][tn], red[3][tn]));
  float ps = 0.f;
  float ex[16];
#pragma unroll
  for (int i = 0; i < 16; i++) { ex[i] = __expf(acc2[i] - mx); ps += ex[i]; }
  __syncthreads();
  red[sg][tn] = ps;
  __syncthreads();
  float inv = 1.f / (red[0][tn] + red[1][tn] + red[2][tn] + red[3][tn]);
  short* krow = Kt + ((size_t)b * N_ + n0 + tn) * S_ + sg * 16;
#pragma unroll
  for (int i = 0; i < 16; i++) krow[i] = f2b(ex[i] * inv);
}

// K2: V = W_v * x + b_v -> bf16 PANEL-TILED Vp[b][n/64][c][64].  1D grid 512, b = bid&7.
__global__ __launch_bounds__(256) void k2_xv(const short* __restrict__ Wvb,
    const float* __restrict__ bv, const short* __restrict__ xt, short* __restrict__ Vp) {
  int bid = blockIdx.x;
  int b = bid & 7, nblk = bid >> 3, n0 = nblk * 64;
  int lane = threadIdx.x & 63, w = threadIdx.x >> 6;
  int lr = lane & 15, lg = lane >> 4;
  f32x4 acc[4][4];
#pragma unroll
  for (int i = 0; i < 4; i++)
#pragma unroll
    for (int j = 0; j < 4; j++) acc[i][j] = {0.f, 0.f, 0.f, 0.f};
  const short* xtb = xt + ((size_t)b * N_ + n0) * C_;
#pragma unroll 1
  for (int ks = 0; ks < 8; ks++) {
    int kb = ks * 32 + lg * 8;
    short8 bfrag[4];
#pragma unroll
    for (int ns = 0; ns < 4; ns++)
      bfrag[ns] = *(const short8*)(xtb + (size_t)(ns * 16 + lr) * C_ + kb);
#pragma unroll
    for (int os = 0; os < 4; os++) {
      short8 af = *(const short8*)(Wvb + (size_t)(w * 64 + os * 16 + lr) * C_ + kb);
#pragma unroll
      for (int ns = 0; ns < 4; ns++)
        acc[os][ns] = __builtin_amdgcn_mfma_f32_16x16x32_bf16(af, bfrag[ns], acc[os][ns], 0, 0, 0);
    }
  }
  short* Vb = Vp + ((size_t)b * 64 + nblk) * (C_ * 64);
#pragma unroll
  for (int os = 0; os < 4; os++) {
#pragma unroll
    for (int r = 0; r < 4; r++) {
      int o = w * 64 + os * 16 + lg * 4 + r;
      float bvo = bv[o];
#pragma unroll
      for (int ns = 0; ns < 4; ns++)
        Vb[(size_t)o * 64 + ns * 16 + lr] = f2b(acc[os][ns][r] + bvo);
    }
  }
}

// K3: inv_rse[b][n] = 1 / sum_m exp2(e2[n,m]).  1D grid 512, b = bid&7 (Kt[b] L2-resident).
__global__ __launch_bounds__(256) void k3_rse(const short* __restrict__ Qt,
    const short* __restrict__ Kt, float* __restrict__ inv_rse) {
  int bid = blockIdx.x;
  int b = bid & 7, n0 = (bid >> 3) * 64;
  int lane = threadIdx.x & 63, w = threadIdx.x >> 6;
  int lr = lane & 15, lg = lane >> 4;
  const short* Qb = Qt + (size_t)b * N_ * S_;
  const short* Kb = Kt + (size_t)b * N_ * S_;
  short8 qf[2];
#pragma unroll
  for (int ks = 0; ks < 2; ks++)
    qf[ks] = *(const short8*)(Qb + (size_t)(n0 + w * 16 + lr) * S_ + ks * 32 + lg * 8);
  short8 kc[4][2], kn[4][2];
#pragma unroll
  for (int ms = 0; ms < 4; ms++)
#pragma unroll
    for (int ks = 0; ks < 2; ks++)
      kc[ms][ks] = *(const short8*)(Kb + (size_t)(ms * 16 + lr) * S_ + ks * 32 + lg * 8);
  float rs[4] = {0.f, 0.f, 0.f, 0.f};
#pragma unroll 1
  for (int it = 0; it < 64; ++it) {
    int itn = (it < 63) ? it + 1 : it;
    int mn = itn * 64;
#pragma unroll
    for (int ms = 0; ms < 4; ms++)
#pragma unroll
      for (int ks = 0; ks < 2; ks++)
        kn[ms][ks] = *(const short8*)(Kb + (size_t)(mn + ms * 16 + lr) * S_ + ks * 32 + lg * 8);
#pragma unroll
    for (int ms = 0; ms < 4; ms++) {
      f32x4 e = {0.f, 0.f, 0.f, 0.f};
#pragma unroll
      for (int ks = 0; ks < 2; ks++)
        e = __builtin_amdgcn_mfma_f32_16x16x32_bf16(qf[ks], kc[ms][ks], e, 0, 0, 0);
#pragma unroll
      for (int r = 0; r < 4; r++) rs[r] += __builtin_amdgcn_exp2f(e[r]);
    }
#pragma unroll
    for (int ms = 0; ms < 4; ms++)
#pragma unroll
      for (int ks = 0; ks < 2; ks++) kc[ms][ks] = kn[ms][ks];
  }
#pragma unroll
  for (int off = 1; off < 16; off <<= 1)
#pragma unroll
    for (int r = 0; r < 4; r++) rs[r] += __shfl_xor(rs[r], off, 64);
  if (lr == 0) {
#pragma unroll
    for (int r = 0; r < 4; r++)
      inv_rse[(size_t)b * N_ + n0 + w * 16 + lg * 4 + r] = 1.f / rs[r];
  }
}

// K4: fused energy->att->PV per (b, 64-wide m tile). 1D grid 512, b = bid&7 so all
// m-blocks of batch b share one XCD's L2 (V 2MB + Qt/Kt 1MB resident -> L2-hit loads).
__global__ __launch_bounds__(256, 2) void k4_att(const short* __restrict__ Qt,
    const short* __restrict__ Kt, const short* __restrict__ Vp,
    const float* __restrict__ inv_rse, short* __restrict__ xrp) {
  int bid = blockIdx.x;
  int b = bid & 7, m0 = (bid >> 3) * 64;
  int lane = threadIdx.x & 63, w = threadIdx.x >> 6;
  int lr = lane & 15, lg = lane >> 4;
  __shared__ short att[2][64][72];  // double-buffered [m][n] tile, 144B rows
  __shared__ float cs_red[4][64];
  const short* Qb = Qt + (size_t)b * N_ * S_;
  const short* Kb = Kt + (size_t)b * N_ * S_;
  const short* Vb = Vp + (size_t)b * 64 * (C_ * 64);
  const float* irb = inv_rse + (size_t)b * N_;
  short8 kfrag[4][2];
#pragma unroll
  for (int ms = 0; ms < 4; ms++)
#pragma unroll
    for (int ks = 0; ks < 2; ks++)
      kfrag[ms][ks] = *(const short8*)(Kb + (size_t)(m0 + ms * 16 + lr) * S_ + ks * 32 + lg * 8);
  f32x4 P[4][4];
#pragma unroll
  for (int i = 0; i < 4; i++)
#pragma unroll
    for (int j = 0; j < 4; j++) P[i][j] = {0.f, 0.f, 0.f, 0.f};
  float csum[4] = {0.f, 0.f, 0.f, 0.f};
  // prefetch iteration 0
  short8 qf[2], vf[2][4];
  float ir[4];
#pragma unroll
  for (int ks = 0; ks < 2; ks++)
    qf[ks] = *(const short8*)(Qb + (size_t)(w * 16 + lr) * S_ + ks * 32 + lg * 8);
#pragma unroll
  for (int ks = 0; ks < 2; ks++)
#pragma unroll
    for (int cs = 0; cs < 4; cs++)
      vf[ks][cs] = *(const short8*)(Vb + (size_t)(w * 64 + cs * 16 + lr) * 64 + ks * 32 + lg * 8);
#pragma unroll
  for (int r = 0; r < 4; r++) ir[r] = irb[w * 16 + lg * 4 + r];
  int buf = 0;
#pragma unroll 1
  for (int it = 0; it < 64; ++it) {
    // QK^T for this tile (registers only)
    f32x4 e[4];
#pragma unroll
    for (int ms = 0; ms < 4; ms++) e[ms] = {0.f, 0.f, 0.f, 0.f};
#pragma unroll
    for (int ms = 0; ms < 4; ms++)
#pragma unroll
      for (int ks = 0; ks < 2; ks++)
        e[ms] = __builtin_amdgcn_mfma_f32_16x16x32_bf16(qf[ks], kfrag[ms][ks], e[ms], 0, 0, 0);
    // issue next-iteration prefetch (lands during exp/pack/barrier/PV)
    int itn = (it < 63) ? it + 1 : it;
    int n2 = itn * 64;
    short8 qn[2], vn[2][4];
    float irn[4];
#pragma unroll
    for (int ks = 0; ks < 2; ks++)
      qn[ks] = *(const short8*)(Qb + (size_t)(n2 + w * 16 + lr) * S_ + ks * 32 + lg * 8);
#pragma unroll
    for (int ks = 0; ks < 2; ks++)
#pragma unroll
      for (int cs = 0; cs < 4; cs++)
        vn[ks][cs] = *(const short8*)(Vb + (size_t)itn * (C_ * 64) +
                                      (size_t)(w * 64 + cs * 16 + lr) * 64 + ks * 32 + lg * 8);
#pragma unroll
    for (int r = 0; r < 4; r++) irn[r] = irb[n2 + w * 16 + lg * 4 + r];
    // att = exp2(e) * inv_rse ; colsum ; pack to bf16 ; LDS write
#pragma unroll
    for (int ms = 0; ms < 4; ms++) {
      float a0 = __builtin_amdgcn_exp2f(e[ms][0]) * ir[0];
      float a1 = __builtin_amdgcn_exp2f(e[ms][1]) * ir[1];
      float a2 = __builtin_amdgcn_exp2f(e[ms][2]) * ir[2];
      float a3 = __builtin_amdgcn_exp2f(e[ms][3]) * ir[3];
      csum[ms] += (a0 + a1) + (a2 + a3);
      int2 pk;
      pk.x = cvtpk(a0, a1);
      pk.y = cvtpk(a2, a3);
      *(int2*)(&att[buf][ms * 16 + lr][w * 16 + lg * 4]) = pk;
    }
    __syncthreads();
    // PV with current V-frags
#pragma unroll
    for (int ks = 0; ks < 2; ks++) {
      short8 bfr[4];
#pragma unroll
      for (int ms = 0; ms < 4; ms++)
        bfr[ms] = *(const short8*)(&att[buf][ms * 16 + lr][ks * 32 + lg * 8]);
#pragma unroll
      for (int cs = 0; cs < 4; cs++)
#pragma unroll
        for (int ms = 0; ms < 4; ms++)
          P[cs][ms] = __builtin_amdgcn_mfma_f32_16x16x32_bf16(vf[ks][cs], bfr[ms], P[cs][ms], 0, 0, 0);
    }
    // rotate prefetch buffers
#pragma unroll
    for (int ks = 0; ks < 2; ks++) {
      qf[ks] = qn[ks];
#pragma unroll
      for (int cs = 0; cs < 4; cs++) vf[ks][cs] = vn[ks][cs];
    }
#pragma unroll
    for (int r = 0; r < 4; r++) ir[r] = irn[r];
    buf ^= 1;
  }
  // column-sum reduce (over n) then normalize P and store
#pragma unroll
  for (int off = 16; off < 64; off <<= 1)
#pragma unroll
    for (int ms = 0; ms < 4; ms++) csum[ms] += __shfl_xor(csum[ms], off, 64);
  if (lg == 0) {
#pragma unroll
    for (int ms = 0; ms < 4; ms++) cs_red[w][ms * 16 + lr] = csum[ms];
  }
  __syncthreads();
  float cinv[4];
#pragma unroll
  for (int ms = 0; ms < 4; ms++) {
    int m = ms * 16 + lr;
    cinv[ms] = 1.f / (1e-9f + cs_red[0][m] + cs_red[1][m] + cs_red[2][m] + cs_red[3][m]);
  }
  short* xb = xrp + ((size_t)b * N_ + m0) * C_;
#pragma unroll
  for (int cs = 0; cs < 4; cs++)
#pragma unroll
    for (int ms = 0; ms < 4; ms++) {
      int2 pk;
      pk.x = cvtpk(P[cs][ms][0] * cinv[ms], P[cs][ms][1] * cinv[ms]);
      pk.y = cvtpk(P[cs][ms][2] * cinv[ms], P[cs][ms][3] * cinv[ms]);
      *(int2*)(xb + (size_t)(ms * 16 + lr) * C_ + w * 64 + cs * 16 + lg * 4) = pk;
    }
}

// K5: out = x + relu(BN(W_t * x_r + b_t))
__global__ __launch_bounds__(256) void k5_out(const short* __restrict__ Wtb,
    const float* __restrict__ bt, const float* __restrict__ gamma,
    const float* __restrict__ beta, const float* __restrict__ mean,
    const float* __restrict__ var, const short* __restrict__ xrp,
    const float* __restrict__ x, float* __restrict__ out) {
  int bid = blockIdx.x;
  int b = bid & 7, m0 = (bid >> 3) * 64;
  int lane = threadIdx.x & 63, w = threadIdx.x >> 6;
  int lr = lane & 15, lg = lane >> 4;
  f32x4 acc[4][4];
#pragma unroll
  for (int i = 0; i < 4; i++)
#pragma unroll
    for (int j = 0; j < 4; j++) acc[i][j] = {0.f, 0.f, 0.f, 0.f};
  const short* xrb = xrp + ((size_t)b * N_ + m0) * C_;
#pragma unroll 1
  for (int ks = 0; ks < 8; ks++) {
    int kb = ks * 32 + lg * 8;
    short8 bfr[4];
#pragma unroll
    for (int ms = 0; ms < 4; ms++)
      bfr[ms] = *(const short8*)(xrb + (size_t)(ms * 16 + lr) * C_ + kb);
#pragma unroll
    for (int os = 0; os < 4; os++) {
      short8 af = *(const short8*)(Wtb + (size_t)(w * 64 + os * 16 + lr) * C_ + kb);
#pragma unroll
      for (int ms = 0; ms < 4; ms++)
        acc[os][ms] = __builtin_amdgcn_mfma_f32_16x16x32_bf16(af, bfr[ms], acc[os][ms], 0, 0, 0);
    }
  }
  const float* xb = x + (size_t)b * C_ * N_ + m0;
  float* ob = out + (size_t)b * C_ * N_ + m0;
#pragma unroll
  for (int os = 0; os < 4; os++)
#pragma unroll
    for (int r = 0; r < 4; r++) {
      int o = w * 64 + os * 16 + lg * 4 + r;
      float bb = bt[o];
      float iv = gamma[o] * rsqrtf(var[o] + 1e-5f);
      float mn = mean[o], be = beta[o];
#pragma unroll
      for (int ms = 0; ms < 4; ms++) {
        int m = ms * 16 + lr;
        float v = (acc[os][ms][r] + bb - mn) * iv + be;
        v = fmaxf(v, 0.f);
        ob[(size_t)o * N_ + m] = xb[(size_t)o * N_ + m] + v;
      }
    }
}

extern "C" void kernel_launch(void* const* d_in, const int* in_sizes, int n_in,
                              void* d_out, int out_size, void* d_ws, size_t ws_size,
                              hipStream_t stream) {
  const float* x     = (const float*)d_in[0];
  const float* Wqk   = (const float*)d_in[1];
  const float* Wk2c  = (const float*)d_in[2];
  const float* Wv    = (const float*)d_in[3];
  const float* bv    = (const float*)d_in[4];
  const float* Wt    = (const float*)d_in[5];
  const float* bt    = (const float*)d_in[6];
  const float* gamma = (const float*)d_in[7];
  const float* beta  = (const float*)d_in[8];
  const float* mean  = (const float*)d_in[9];
  const float* var   = (const float*)d_in[10];
  const int*   idx   = (const int*)d_in[11];
  float* out = (float*)d_out;

  char* ws = (char*)d_ws;
  size_t off = 0;
  auto alloc = [&](size_t bytes) -> void* {
    void* p = ws + off;
    off = (off + bytes + 255) & ~(size_t)255;
    return p;
  };
  short* xt   = (short*)alloc((size_t)B_ * N_ * C_ * 2);
  short* Qt   = (short*)alloc((size_t)B_ * N_ * S_ * 2);
  short* Kt   = (short*)alloc((size_t)B_ * N_ * S_ * 2);
  short* Vp   = (short*)alloc((size_t)B_ * C_ * N_ * 2);
  float* irse = (float*)alloc((size_t)B_ * N_ * 4);
  short* xrp  = (short*)alloc((size_t)B_ * N_ * C_ * 2);
  short* Wvb  = (short*)alloc((size_t)C_ * C_ * 2);
  short* Wtb  = (short*)alloc((size_t)C_ * C_ * 2);

  kw_conv<<<dim3(64), 256, 0, stream>>>(Wv, Wt, Wvb, Wtb);
  k0_transpose<<<dim3(2048), 256, 0, stream>>>(x, xt);
  k1_qk<<<dim3(512), dim3(64, 4), 0, stream>>>(x, Wqk, Wk2c, idx, Qt, Kt);
  k2_xv<<<dim3(512), 256, 0, stream>>>(Wvb, bv, xt, Vp);
  k3_rse<<<dim3(512), 256, 0, stream>>>(Qt, Kt, irse);
  k4_att<<<dim3(512), 256, 0, stream>>>(Qt, Kt, Vp, irse, xrp);
  k5_out<<<dim3(512), 256, 0, stream>>>(Wtb, bt, gamma, beta, mean, var, xrp, x, out);
}

// Round 4
// 338.001 us; speedup vs baseline: 1.4180x; 1.4180x over previous
//
#include <hip/hip_runtime.h>
#include <hip/hip_bf16.h>

#define B_ 8
#define C_ 256
#define N_ 4096
#define S_ 64
#define LOG2E 1.4426950408889634f

typedef __attribute__((ext_vector_type(8))) short short8;
typedef __attribute__((ext_vector_type(4))) float f32x4;

__device__ __forceinline__ short f2b(float f) {
  unsigned u = __float_as_uint(f);
  unsigned r = (u + 0x7FFFu + ((u >> 16) & 1u)) >> 16;
  return (short)(r & 0xFFFFu);
}

__device__ __forceinline__ int cvtpk(float lo, float hi) {
  int r;
  asm("v_cvt_pk_bf16_f32 %0, %1, %2" : "=v"(r) : "v"(lo), "v"(hi));
  return r;
}

// ---- FRAG format: F[rtile][ks][lane][8] shorts; per (rtile,ks) = 512 shorts (1KB),
// lane = (r&15) + 16*((k>>3)&3), j = k&7.  One wave load = 1KB fully coalesced. ----

// K0: x (f32 [b][c][n]) -> Xf frag-major (rows n, k = c): [b][ntile 256][ks 8][64][8]
__global__ __launch_bounds__(256) void k0_transpose(const float* __restrict__ x,
                                                    short* __restrict__ Xf) {
  __shared__ float tile[64][65];   // [c_local][n_local]
  int bid = blockIdx.x;
  int b = bid & 7;
  int rest = bid >> 3;            // 4 c-blocks x 64 n-blocks
  int c0 = (rest & 3) * 64, n0 = (rest >> 2) * 64;
  int tn = threadIdx.x & 63, tc = threadIdx.x >> 6;
  const float* xb = x + ((size_t)b * C_ + c0) * N_ + n0;
#pragma unroll
  for (int i = 0; i < 16; i++) {
    int c = tc * 16 + i;
    tile[c][tn] = xb[(size_t)c * N_ + tn];
  }
  __syncthreads();
  // 512 frag-runs per block (4 ntl x 2 ksl x 64 lanes); 2 per thread
#pragma unroll
  for (int rr = 0; rr < 2; rr++) {
    int run = rr * 256 + threadIdx.x;
    int ntl = run >> 7, ksl = (run >> 6) & 1, ln = run & 63;
    short8 o;
#pragma unroll
    for (int j = 0; j < 8; j++) {
      int cl = ksl * 32 + ((ln >> 4) & 3) * 8 + j;
      int nl = ntl * 16 + (ln & 15);
      o[j] = f2b(tile[cl][nl]);
    }
    size_t off = ((((size_t)b * 256 + (n0 >> 4) + ntl) * 8 + (c0 >> 5) + ksl) * 64 + ln) * 8;
    *(short8*)(Xf + off) = o;
  }
}

// KW: W_v, W_t f32 row-major [o][c] -> frag-major (rows o, k=c): [otile16][ks8][64][8]
__global__ __launch_bounds__(256) void kw_conv(const float* __restrict__ Wv,
    const float* __restrict__ Wt, short* __restrict__ Wvf, short* __restrict__ Wtf) {
  int t = blockIdx.x * 256 + threadIdx.x;           // 16384 threads
  const float* src = (t < 8192) ? Wv : Wt;
  short* dst = (t < 8192) ? Wvf : Wtf;
  int i = (t & 8191) * 8;
  int o = i >> 8, c0c = i & 255;
  short8 v;
#pragma unroll
  for (int j = 0; j < 8; j++) v[j] = f2b(src[i + j]);
  int lane = (o & 15) + 16 * ((c0c >> 3) & 3);
  size_t off = ((((size_t)(o >> 4)) * 8 + (c0c >> 5)) * 64 + lane) * 8;
  *(short8*)(dst + off) = v;
}

// K1: Qf frag (rows n, k=s, PRE-SCALED log2e), Kf frag (rows m, k=s, softmaxed)
__global__ __launch_bounds__(256) void k1_qk(const float* __restrict__ x,
    const float* __restrict__ Wqk, const float* __restrict__ Wk2c,
    const int* __restrict__ idx, short* __restrict__ Qf, short* __restrict__ Kf) {
  int bid = blockIdx.x;
  int b = bid & 7, n0 = (bid >> 3) * 64;
  int tn = threadIdx.x;
  int sg = __builtin_amdgcn_readfirstlane(threadIdx.y);
  const float* xb = x + (size_t)b * C_ * N_ + n0 + tn;
  float acc[16];
#pragma unroll
  for (int i = 0; i < 16; i++) acc[i] = 0.f;
  for (int c = 0; c < C_; c += 4) {
    float x0 = xb[(size_t)c * N_];
    float x1 = xb[(size_t)(c + 1) * N_];
    float x2 = xb[(size_t)(c + 2) * N_];
    float x3 = xb[(size_t)(c + 3) * N_];
#pragma unroll
    for (int i = 0; i < 16; i++) {
      const float* wr = Wqk + (sg * 16 + i) * C_ + c;
      acc[i] += wr[0] * x0 + wr[1] * x1 + wr[2] * x2 + wr[3] * x3;
    }
  }
  __shared__ float q_lds[64][65];
  __shared__ float red[4][64];
#pragma unroll
  for (int i = 0; i < 16; i++) q_lds[sg * 16 + i][tn] = acc[i];
  {
    // frag store: rows n = n0+tn, s = sg*16 + i
    size_t base = (((size_t)b * 256 + (n0 >> 4) + (tn >> 4)) * 2 + (sg >> 1)) * 64;
    int l0 = (tn & 15) + 16 * ((2 * sg) & 3);
    int l1 = (tn & 15) + 16 * ((2 * sg + 1) & 3);
    short8 o0, o1;
#pragma unroll
    for (int i = 0; i < 8; i++) { o0[i] = f2b(acc[i] * LOG2E); o1[i] = f2b(acc[i + 8] * LOG2E); }
    *(short8*)(Qf + (base + l0) * 8) = o0;
    *(short8*)(Qf + (base + l1) * 8) = o1;
  }
  __syncthreads();
  float acc2[16];
#pragma unroll
  for (int i = 0; i < 16; i++) acc2[i] = 0.f;
  for (int h = 0; h < 64; h += 4) {
    float q0 = q_lds[h][tn], q1 = q_lds[h + 1][tn];
    float q2 = q_lds[h + 2][tn], q3 = q_lds[h + 3][tn];
#pragma unroll
    for (int i = 0; i < 16; i++) {
      const float* wr = Wk2c + (sg * 16 + i) * 128 + h;
      acc2[i] += wr[0] * q0 + wr[1] * q1 + wr[2] * q2 + wr[3] * q3;
    }
  }
  for (int h = 0; h < 64; h += 4) {
    float g0 = xb[(size_t)idx[h] * N_];
    float g1 = xb[(size_t)idx[h + 1] * N_];
    float g2 = xb[(size_t)idx[h + 2] * N_];
    float g3 = xb[(size_t)idx[h + 3] * N_];
#pragma unroll
    for (int i = 0; i < 16; i++) {
      const float* wr = Wk2c + (sg * 16 + i) * 128 + 64 + h;
      acc2[i] += wr[0] * g0 + wr[1] * g1 + wr[2] * g2 + wr[3] * g3;
    }
  }
  float pm = acc2[0];
#pragma unroll
  for (int i = 1; i < 16; i++) pm = fmaxf(pm, acc2[i]);
  red[sg][tn] = pm;
  __syncthreads();
  float mx = fmaxf(fmaxf(red[0][tn], red[1][tn]), fmaxf(red[2][tn], red[3][tn]));
  float ps = 0.f;
  float ex[16];
#pragma unroll
  for (int i = 0; i < 16; i++) { ex[i] = __expf(acc2[i] - mx); ps += ex[i]; }
  __syncthreads();
  red[sg][tn] = ps;
  __syncthreads();
  float inv = 1.f / (red[0][tn] + red[1][tn] + red[2][tn] + red[3][tn]);
  {
    size_t base = (((size_t)b * 256 + (n0 >> 4) + (tn >> 4)) * 2 + (sg >> 1)) * 64;
    int l0 = (tn & 15) + 16 * ((2 * sg) & 3);
    int l1 = (tn & 15) + 16 * ((2 * sg + 1) & 3);
    short8 o0, o1;
#pragma unroll
    for (int i = 0; i < 8; i++) { o0[i] = f2b(ex[i] * inv); o1[i] = f2b(ex[i + 8] * inv); }
    *(short8*)(Kf + (base + l0) * 8) = o0;
    *(short8*)(Kf + (base + l1) * 8) = o1;
  }
}

// K2: V = W_v*x + b_v -> Vf frag-major (rows c, k=n): [b][nks 128][ctile 16][64][8]
__global__ __launch_bounds__(256) void k2_xv(const short* __restrict__ Wvf,
    const float* __restrict__ bv, const short* __restrict__ Xf, short* __restrict__ Vf) {
  int bid = blockIdx.x;
  int b = bid & 7, nblk = bid >> 3;
  int lane = threadIdx.x & 63, w = threadIdx.x >> 6;
  int lr = lane & 15, lg = lane >> 4;
  __shared__ short Vt[64][264];   // [n_local][c]
  f32x4 acc[4][4];
#pragma unroll
  for (int i = 0; i < 4; i++)
#pragma unroll
    for (int j = 0; j < 4; j++) acc[i][j] = {0.f, 0.f, 0.f, 0.f};
#pragma unroll 1
  for (int ks = 0; ks < 8; ks++) {
    short8 bfrag[4];
#pragma unroll
    for (int ns = 0; ns < 4; ns++)
      bfrag[ns] = *(const short8*)(Xf + ((((size_t)b * 256 + nblk * 4 + ns) * 8 + ks) * 64 + lane) * 8);
#pragma unroll
    for (int os = 0; os < 4; os++) {
      short8 af = *(const short8*)(Wvf + ((((size_t)(4 * w + os)) * 8 + ks) * 64 + lane) * 8);
#pragma unroll
      for (int ns = 0; ns < 4; ns++)
        acc[os][ns] = __builtin_amdgcn_mfma_f32_16x16x32_bf16(af, bfrag[ns], acc[os][ns], 0, 0, 0);
    }
  }
  // bounce through LDS to emit frag-major
#pragma unroll
  for (int os = 0; os < 4; os++) {
    int c0 = w * 64 + os * 16 + lg * 4;
    float b0 = bv[c0], b1 = bv[c0 + 1], b2 = bv[c0 + 2], b3 = bv[c0 + 3];
#pragma unroll
    for (int ns = 0; ns < 4; ns++) {
      int2 pk;
      pk.x = cvtpk(acc[os][ns][0] + b0, acc[os][ns][1] + b1);
      pk.y = cvtpk(acc[os][ns][2] + b2, acc[os][ns][3] + b3);
      *(int2*)(&Vt[ns * 16 + lr][c0]) = pk;
    }
  }
  __syncthreads();
#pragma unroll
  for (int rr = 0; rr < 8; rr++) {
    int run = rr * 256 + threadIdx.x;
    int ksl = run >> 10, ctile = (run >> 6) & 15, ln = run & 63;
    short8 o;
#pragma unroll
    for (int j = 0; j < 8; j++)
      o[j] = Vt[ksl * 32 + ((ln >> 4) & 3) * 8 + j][ctile * 16 + (ln & 15)];
    size_t off = ((((size_t)b * 128 + 2 * nblk + ksl) * 16 + ctile) * 64 + ln) * 8;
    *(short8*)(Vf + off) = o;
  }
}

// K3: inv_rse[b][n] = 1/sum_m exp2(e).  Frag loads, 1-deep prefetch, no LDS.
__global__ __launch_bounds__(256) void k3_rse(const short* __restrict__ Qf,
    const short* __restrict__ Kf, float* __restrict__ inv_rse) {
  int bid = blockIdx.x;
  int b = bid & 7, n0 = (bid >> 3) * 64;
  int lane = threadIdx.x & 63, w = threadIdx.x >> 6;
  int lg = lane >> 4;
  const short* Qb = Qf + (size_t)b * 256 * 2 * 512;
  const short* Kb = Kf + (size_t)b * 256 * 2 * 512;
  short8 qf[2];
#pragma unroll
  for (int ks = 0; ks < 2; ks++)
    qf[ks] = *(const short8*)(Qb + ((((size_t)(n0 >> 4) + w) * 2 + ks) * 64 + lane) * 8);
  short8 kc[4][2], kn[4][2];
#pragma unroll
  for (int ms = 0; ms < 4; ms++)
#pragma unroll
    for (int ks = 0; ks < 2; ks++)
      kc[ms][ks] = *(const short8*)(Kb + ((((size_t)ms) * 2 + ks) * 64 + lane) * 8);
  float rs[4] = {0.f, 0.f, 0.f, 0.f};
#pragma unroll 1
  for (int it = 0; it < 64; ++it) {
    int itn = (it < 63) ? it + 1 : it;
#pragma unroll
    for (int ms = 0; ms < 4; ms++)
#pragma unroll
      for (int ks = 0; ks < 2; ks++)
        kn[ms][ks] = *(const short8*)(Kb + ((((size_t)(itn * 4 + ms)) * 2 + ks) * 64 + lane) * 8);
#pragma unroll
    for (int ms = 0; ms < 4; ms++) {
      f32x4 e = {0.f, 0.f, 0.f, 0.f};
#pragma unroll
      for (int ks = 0; ks < 2; ks++)
        e = __builtin_amdgcn_mfma_f32_16x16x32_bf16(qf[ks], kc[ms][ks], e, 0, 0, 0);
#pragma unroll
      for (int r = 0; r < 4; r++) rs[r] += __builtin_amdgcn_exp2f(e[r]);
    }
#pragma unroll
    for (int ms = 0; ms < 4; ms++)
#pragma unroll
      for (int ks = 0; ks < 2; ks++) kc[ms][ks] = kn[ms][ks];
  }
#pragma unroll
  for (int off = 1; off < 16; off <<= 1)
#pragma unroll
    for (int r = 0; r < 4; r++) rs[r] += __shfl_xor(rs[r], off, 64);
  if ((lane & 15) == 0) {
#pragma unroll
    for (int r = 0; r < 4; r++)
      inv_rse[(size_t)b * N_ + n0 + w * 16 + lg * 4 + r] = 1.f / rs[r];
  }
}

// K4: fused energy->att->PV. 128 n per barrier (32 iters), frag-major loads,
// dbuf att LDS, output xrp frag-major via LDS bounce.
__global__ __launch_bounds__(256, 2) void k4_att(const short* __restrict__ Qf,
    const short* __restrict__ Kf, const short* __restrict__ Vf,
    const float* __restrict__ inv_rse, short* __restrict__ Rf) {
  int bid = blockIdx.x;
  int b = bid & 7, mblk = bid >> 3, m0 = mblk * 64;
  int lane = threadIdx.x & 63, w = threadIdx.x >> 6;
  int lr = lane & 15, lg = lane >> 4;
  __shared__ short att[2][64][136];   // dbuf [m][n 128 + 8 pad]
  __shared__ float cs_red[4][64];
  const short* Qb = Qf + (size_t)b * 256 * 2 * 512;
  const short* Kb = Kf + (size_t)b * 256 * 2 * 512;
  const short* Vb = Vf + (size_t)b * 128 * 16 * 512;
  const float* irb = inv_rse + (size_t)b * N_;
  short8 kfrag[4][2];
#pragma unroll
  for (int ms = 0; ms < 4; ms++)
#pragma unroll
    for (int ks = 0; ks < 2; ks++)
      kfrag[ms][ks] = *(const short8*)(Kb + ((((size_t)(mblk * 4 + ms)) * 2 + ks) * 64 + lane) * 8);
  f32x4 P[4][4];
#pragma unroll
  for (int i = 0; i < 4; i++)
#pragma unroll
    for (int j = 0; j < 4; j++) P[i][j] = {0.f, 0.f, 0.f, 0.f};
  float csum[4] = {0.f, 0.f, 0.f, 0.f};
  // prefetch iter-0 Q frags (2 halves x 2 ks)
  short8 qf[2][2];
#pragma unroll
  for (int t = 0; t < 2; t++)
#pragma unroll
    for (int ks = 0; ks < 2; ks++)
      qf[t][ks] = *(const short8*)(Qb + ((((size_t)(t * 4 + w)) * 2 + ks) * 64 + lane) * 8);
  int buf = 0;
#pragma unroll 1
  for (int it2 = 0; it2 < 32; ++it2) {
    // ---- QK^T for both 64-halves ----
    f32x4 e[2][4];
#pragma unroll
    for (int t = 0; t < 2; t++) {
#pragma unroll
      for (int ms = 0; ms < 4; ms++) {
        f32x4 a = {0.f, 0.f, 0.f, 0.f};
#pragma unroll
        for (int ks = 0; ks < 2; ks++)
          a = __builtin_amdgcn_mfma_f32_16x16x32_bf16(qf[t][ks], kfrag[ms][ks], a, 0, 0, 0);
        e[t][ms] = a;
      }
    }
    // ---- issue V loads for all 4 n32-chunks (land during exp/pack/barrier) ----
    short8 vf[4][4];
#pragma unroll
    for (int kk = 0; kk < 4; kk++)
#pragma unroll
      for (int cs = 0; cs < 4; cs++)
        vf[kk][cs] = *(const short8*)(Vb + ((((size_t)(it2 * 4 + kk)) * 16 + 4 * w + cs) * 64 + lane) * 8);
    // ---- prefetch next-iter Q ----
    int itn = (it2 < 31) ? it2 + 1 : it2;
    short8 qn[2][2];
#pragma unroll
    for (int t = 0; t < 2; t++)
#pragma unroll
      for (int ks = 0; ks < 2; ks++)
        qn[t][ks] = *(const short8*)(Qb + ((((size_t)(itn * 8 + t * 4 + w)) * 2 + ks) * 64 + lane) * 8);
    // ---- exp2 * inv_rse, colsum, pack, LDS write ----
#pragma unroll
    for (int t = 0; t < 2; t++) {
      float ir[4];
#pragma unroll
      for (int r = 0; r < 4; r++) ir[r] = irb[it2 * 128 + t * 64 + w * 16 + lg * 4 + r];
#pragma unroll
      for (int ms = 0; ms < 4; ms++) {
        float a0 = __builtin_amdgcn_exp2f(e[t][ms][0]) * ir[0];
        float a1 = __builtin_amdgcn_exp2f(e[t][ms][1]) * ir[1];
        float a2 = __builtin_amdgcn_exp2f(e[t][ms][2]) * ir[2];
        float a3 = __builtin_amdgcn_exp2f(e[t][ms][3]) * ir[3];
        csum[ms] += (a0 + a1) + (a2 + a3);
        int2 pk;
        pk.x = cvtpk(a0, a1);
        pk.y = cvtpk(a2, a3);
        *(int2*)(&att[buf][ms * 16 + lr][t * 64 + w * 16 + lg * 4]) = pk;
      }
    }
    __syncthreads();
    // ---- PV over 128 n ----
#pragma unroll
    for (int kk = 0; kk < 4; kk++) {
      short8 bfr[4];
#pragma unroll
      for (int ms = 0; ms < 4; ms++)
        bfr[ms] = *(const short8*)(&att[buf][ms * 16 + lr][kk * 32 + lg * 8]);
#pragma unroll
      for (int cs = 0; cs < 4; cs++)
#pragma unroll
        for (int ms = 0; ms < 4; ms++)
          P[cs][ms] = __builtin_amdgcn_mfma_f32_16x16x32_bf16(vf[kk][cs], bfr[ms], P[cs][ms], 0, 0, 0);
    }
#pragma unroll
    for (int t = 0; t < 2; t++)
#pragma unroll
      for (int ks = 0; ks < 2; ks++) qf[t][ks] = qn[t][ks];
    buf ^= 1;
  }
  // ---- column-sum reduce, normalize ----
#pragma unroll
  for (int off = 16; off < 64; off <<= 1)
#pragma unroll
    for (int ms = 0; ms < 4; ms++) csum[ms] += __shfl_xor(csum[ms], off, 64);
  if (lg == 0) {
#pragma unroll
    for (int ms = 0; ms < 4; ms++) cs_red[w][ms * 16 + lr] = csum[ms];
  }
  __syncthreads();   // also: all PV att-reads done -> safe to reuse att as Rt
  float cinv[4];
#pragma unroll
  for (int ms = 0; ms < 4; ms++) {
    int m = ms * 16 + lr;
    cinv[ms] = 1.f / (1e-9f + cs_red[0][m] + cs_red[1][m] + cs_red[2][m] + cs_red[3][m]);
  }
  // ---- emit xrp frag-major via LDS bounce (reuse att storage as Rt[64][264]) ----
  short* Rt = &att[0][0][0];
#pragma unroll
  for (int cs = 0; cs < 4; cs++) {
    int c0 = w * 64 + cs * 16 + lg * 4;
#pragma unroll
    for (int ms = 0; ms < 4; ms++) {
      int2 pk;
      pk.x = cvtpk(P[cs][ms][0] * cinv[ms], P[cs][ms][1] * cinv[ms]);
      pk.y = cvtpk(P[cs][ms][2] * cinv[ms], P[cs][ms][3] * cinv[ms]);
      *(int2*)(Rt + (ms * 16 + lr) * 264 + c0) = pk;
    }
  }
  __syncthreads();
#pragma unroll
  for (int rr = 0; rr < 8; rr++) {
    int run = rr * 256 + threadIdx.x;
    int mtl = run >> 9, ksc = (run >> 6) & 7, ln = run & 63;
    short8 o;
#pragma unroll
    for (int j = 0; j < 8; j++)
      o[j] = Rt[(mtl * 16 + (ln & 15)) * 264 + ksc * 32 + ((ln >> 4) & 3) * 8 + j];
    size_t off = ((((size_t)b * 256 + (m0 >> 4) + mtl) * 8 + ksc) * 64 + ln) * 8;
    *(short8*)(Rf + off) = o;
  }
}

// K5: out = x + relu(BN(W_t * x_r + b_t)); frag-major loads.
__global__ __launch_bounds__(256) void k5_out(const short* __restrict__ Wtf,
    const float* __restrict__ bt, const float* __restrict__ gamma,
    const float* __restrict__ beta, const float* __restrict__ mean,
    const float* __restrict__ var, const short* __restrict__ Rf,
    const float* __restrict__ x, float* __restrict__ out) {
  int bid = blockIdx.x;
  int b = bid & 7, m0 = (bid >> 3) * 64;
  int lane = threadIdx.x & 63, w = threadIdx.x >> 6;
  int lr = lane & 15, lg = lane >> 4;
  f32x4 acc[4][4];
#pragma unroll
  for (int i = 0; i < 4; i++)
#pragma unroll
    for (int j = 0; j < 4; j++) acc[i][j] = {0.f, 0.f, 0.f, 0.f};
#pragma unroll 1
  for (int ks = 0; ks < 8; ks++) {
    short8 bfr[4];
#pragma unroll
    for (int ms = 0; ms < 4; ms++)
      bfr[ms] = *(const short8*)(Rf + ((((size_t)b * 256 + (m0 >> 4) + ms) * 8 + ks) * 64 + lane) * 8);
#pragma unroll
    for (int os = 0; os < 4; os++) {
      short8 af = *(const short8*)(Wtf + ((((size_t)(4 * w + os)) * 8 + ks) * 64 + lane) * 8);
#pragma unroll
      for (int ms = 0; ms < 4; ms++)
        acc[os][ms] = __builtin_amdgcn_mfma_f32_16x16x32_bf16(af, bfr[ms], acc[os][ms], 0, 0, 0);
    }
  }
  const float* xb = x + (size_t)b * C_ * N_ + m0;
  float* ob = out + (size_t)b * C_ * N_ + m0;
#pragma unroll
  for (int os = 0; os < 4; os++)
#pragma unroll
    for (int r = 0; r < 4; r++) {
      int o = w * 64 + os * 16 + lg * 4 + r;
      float bb = bt[o];
      float iv = gamma[o] * rsqrtf(var[o] + 1e-5f);
      float mn = mean[o], be = beta[o];
#pragma unroll
      for (int ms = 0; ms < 4; ms++) {
        int m = ms * 16 + lr;
        float v = (acc[os][ms][r] + bb - mn) * iv + be;
        v = fmaxf(v, 0.f);
        ob[(size_t)o * N_ + m] = xb[(size_t)o * N_ + m] + v;
      }
    }
}

extern "C" void kernel_launch(void* const* d_in, const int* in_sizes, int n_in,
                              void* d_out, int out_size, void* d_ws, size_t ws_size,
                              hipStream_t stream) {
  const float* x     = (const float*)d_in[0];
  const float* Wqk   = (const float*)d_in[1];
  const float* Wk2c  = (const float*)d_in[2];
  const float* Wv    = (const float*)d_in[3];
  const float* bv    = (const float*)d_in[4];
  const float* Wt    = (const float*)d_in[5];
  const float* bt    = (const float*)d_in[6];
  const float* gamma = (const float*)d_in[7];
  const float* beta  = (const float*)d_in[8];
  const float* mean  = (const float*)d_in[9];
  const float* var   = (const float*)d_in[10];
  const int*   idx   = (const int*)d_in[11];
  float* out = (float*)d_out;

  char* ws = (char*)d_ws;
  size_t off = 0;
  auto alloc = [&](size_t bytes) -> void* {
    void* p = ws + off;
    off = (off + bytes + 255) & ~(size_t)255;
    return p;
  };
  short* Xf   = (short*)alloc((size_t)B_ * N_ * C_ * 2);
  short* Qf   = (short*)alloc((size_t)B_ * N_ * S_ * 2);
  short* Kf   = (short*)alloc((size_t)B_ * N_ * S_ * 2);
  short* Vf   = (short*)alloc((size_t)B_ * C_ * N_ * 2);
  float* irse = (float*)alloc((size_t)B_ * N_ * 4);
  short* Rf   = (short*)alloc((size_t)B_ * N_ * C_ * 2);
  short* Wvf  = (short*)alloc((size_t)C_ * C_ * 2);
  short* Wtf  = (short*)alloc((size_t)C_ * C_ * 2);

  kw_conv<<<dim3(64), 256, 0, stream>>>(Wv, Wt, Wvf, Wtf);
  k0_transpose<<<dim3(2048), 256, 0, stream>>>(x, Xf);
  k1_qk<<<dim3(512), dim3(64, 4), 0, stream>>>(x, Wqk, Wk2c, idx, Qf, Kf);
  k2_xv<<<dim3(512), 256, 0, stream>>>(Wvf, bv, Xf, Vf);
  k3_rse<<<dim3(512), 256, 0, stream>>>(Qf, Kf, irse);
  k4_att<<<dim3(512), 256, 0, stream>>>(Qf, Kf, Vf, irse, Rf);
  k5_out<<<dim3(512), 256, 0, stream>>>(Wtf, bt, gamma, beta, mean, var, Rf, x, out);
}

// Round 6
// 337.385 us; speedup vs baseline: 1.4206x; 1.0018x over previous
//
#include <hip/hip_runtime.h>
#include <hip/hip_bf16.h>

#define B_ 8
#define C_ 256
#define N_ 4096
#define S_ 64
#define LOG2E 1.4426950408889634f

typedef __attribute__((ext_vector_type(8))) short short8;
typedef __attribute__((ext_vector_type(4))) float f32x4;

__device__ __forceinline__ short f2b(float f) {
  unsigned u = __float_as_uint(f);
  unsigned r = (u + 0x7FFFu + ((u >> 16) & 1u)) >> 16;
  return (short)(r & 0xFFFFu);
}

__device__ __forceinline__ int cvtpk(float lo, float hi) {
  int r;
  asm("v_cvt_pk_bf16_f32 %0, %1, %2" : "=v"(r) : "v"(lo), "v"(hi));
  return r;
}

// ---- FRAG format: F[rtile][ks][lane][8] shorts; lane = (r&15) + 16*((k>>3)&3),
// j = k&7. One wave load = 1KB fully coalesced. ----

// KW: W_v, W_t f32 row-major [o][c] -> frag-major (rows o, k=c): [otile16][ks8][64][8]
__global__ __launch_bounds__(256) void kw_conv(const float* __restrict__ Wv,
    const float* __restrict__ Wt, short* __restrict__ Wvf, short* __restrict__ Wtf) {
  int t = blockIdx.x * 256 + threadIdx.x;           // 16384 threads
  const float* src = (t < 8192) ? Wv : Wt;
  short* dst = (t < 8192) ? Wvf : Wtf;
  int i = (t & 8191) * 8;
  int o = i >> 8, c0c = i & 255;
  short8 v;
#pragma unroll
  for (int j = 0; j < 8; j++) v[j] = f2b(src[i + j]);
  int lane = (o & 15) + 16 * ((c0c >> 3) & 3);
  size_t off = ((((size_t)(o >> 4)) * 8 + (c0c >> 5)) * 64 + lane) * 8;
  *(short8*)(dst + off) = v;
}

// K1: Qf frag (rows n, k=s, PRE-SCALED log2e), Kf frag (softmaxed), AND Xf frag
// (rows n, k=c) — k0 fused in: k1 already streams all of x for this n-tile.
__global__ __launch_bounds__(256) void k1_qk(const float* __restrict__ x,
    const float* __restrict__ Wqk, const float* __restrict__ Wk2c,
    const int* __restrict__ idx, short* __restrict__ Qf, short* __restrict__ Kf,
    short* __restrict__ Xf) {
  int bid = blockIdx.x;
  int b = bid & 7, n0 = (bid >> 3) * 64;
  int tn = threadIdx.x;
  int sg = __builtin_amdgcn_readfirstlane(threadIdx.y);
  const float* xb = x + (size_t)b * C_ * N_ + n0 + tn;
  __shared__ short xls[256][73];     // bf16 x tile [c][n_local]
  __shared__ float q_lds[64][65];
  __shared__ float red[4][64];
  // phase 0: each sg-wave stages its c-range into xls (L1-warms the main loop too)
#pragma unroll 4
  for (int i = 0; i < 64; i++) {
    int c = sg * 64 + i;
    xls[c][tn] = f2b(xb[(size_t)c * N_]);
  }
  float acc[16];
#pragma unroll
  for (int i = 0; i < 16; i++) acc[i] = 0.f;
  for (int c = 0; c < C_; c += 4) {
    float x0 = xb[(size_t)c * N_];
    float x1 = xb[(size_t)(c + 1) * N_];
    float x2 = xb[(size_t)(c + 2) * N_];
    float x3 = xb[(size_t)(c + 3) * N_];
#pragma unroll
    for (int i = 0; i < 16; i++) {
      const float* wr = Wqk + (sg * 16 + i) * C_ + c;
      acc[i] += wr[0] * x0 + wr[1] * x1 + wr[2] * x2 + wr[3] * x3;
    }
  }
#pragma unroll
  for (int i = 0; i < 16; i++) q_lds[sg * 16 + i][tn] = acc[i];
  {
    size_t base = (((size_t)b * 256 + (n0 >> 4) + (tn >> 4)) * 2 + (sg >> 1)) * 64;
    int l0 = (tn & 15) + 16 * ((2 * sg) & 3);
    int l1 = (tn & 15) + 16 * ((2 * sg + 1) & 3);
    short8 o0, o1;
#pragma unroll
    for (int i = 0; i < 8; i++) { o0[i] = f2b(acc[i] * LOG2E); o1[i] = f2b(acc[i + 8] * LOG2E); }
    *(short8*)(Qf + (base + l0) * 8) = o0;
    *(short8*)(Qf + (base + l1) * 8) = o1;
  }
  __syncthreads();
  // Xf frag emission from xls (32 runs, wave sg handles run 4i+sg)
#pragma unroll
  for (int i = 0; i < 8; i++) {
    int run = i * 4 + sg;
    int ntl = run >> 3, ks = run & 7;
    short8 o;
#pragma unroll
    for (int j = 0; j < 8; j++)
      o[j] = xls[ks * 32 + ((tn >> 4) & 3) * 8 + j][ntl * 16 + (tn & 15)];
    size_t off = ((((size_t)b * 256 + (n0 >> 4) + ntl) * 8 + ks) * 64 + tn) * 8;
    *(short8*)(Xf + off) = o;
  }
  float acc2[16];
#pragma unroll
  for (int i = 0; i < 16; i++) acc2[i] = 0.f;
  for (int h = 0; h < 64; h += 4) {
    float q0 = q_lds[h][tn], q1 = q_lds[h + 1][tn];
    float q2 = q_lds[h + 2][tn], q3 = q_lds[h + 3][tn];
#pragma unroll
    for (int i = 0; i < 16; i++) {
      const float* wr = Wk2c + (sg * 16 + i) * 128 + h;
      acc2[i] += wr[0] * q0 + wr[1] * q1 + wr[2] * q2 + wr[3] * q3;
    }
  }
  for (int h = 0; h < 64; h += 4) {
    float g0 = xb[(size_t)idx[h] * N_];
    float g1 = xb[(size_t)idx[h + 1] * N_];
    float g2 = xb[(size_t)idx[h + 2] * N_];
    float g3 = xb[(size_t)idx[h + 3] * N_];
#pragma unroll
    for (int i = 0; i < 16; i++) {
      const float* wr = Wk2c + (sg * 16 + i) * 128 + 64 + h;
      acc2[i] += wr[0] * g0 + wr[1] * g1 + wr[2] * g2 + wr[3] * g3;
    }
  }
  float pm = acc2[0];
#pragma unroll
  for (int i = 1; i < 16; i++) pm = fmaxf(pm, acc2[i]);
  red[sg][tn] = pm;
  __syncthreads();
  float mx = fmaxf(fmaxf(red[0][tn], red[1][tn]), fmaxf(red[2][tn], red[3][tn]));
  float ps = 0.f;
  float ex[16];
#pragma unroll
  for (int i = 0; i < 16; i++) { ex[i] = __expf(acc2[i] - mx); ps += ex[i]; }
  __syncthreads();
  red[sg][tn] = ps;
  __syncthreads();
  float inv = 1.f / (red[0][tn] + red[1][tn] + red[2][tn] + red[3][tn]);
  {
    size_t base = (((size_t)b * 256 + (n0 >> 4) + (tn >> 4)) * 2 + (sg >> 1)) * 64;
    int l0 = (tn & 15) + 16 * ((2 * sg) & 3);
    int l1 = (tn & 15) + 16 * ((2 * sg + 1) & 3);
    short8 o0, o1;
#pragma unroll
    for (int i = 0; i < 8; i++) { o0[i] = f2b(ex[i] * inv); o1[i] = f2b(ex[i + 8] * inv); }
    *(short8*)(Kf + (base + l0) * 8) = o0;
    *(short8*)(Kf + (base + l1) * 8) = o1;
  }
}

// K2: V = W_v*x + b_v -> Vf frag-major (rows c, k=n): [b][nks 128][ctile 16][64][8]
__global__ __launch_bounds__(256) void k2_xv(const short* __restrict__ Wvf,
    const float* __restrict__ bv, const short* __restrict__ Xf, short* __restrict__ Vf) {
  int bid = blockIdx.x;
  int b = bid & 7, nblk = bid >> 3;
  int lane = threadIdx.x & 63, w = threadIdx.x >> 6;
  int lr = lane & 15, lg = lane >> 4;
  __shared__ short Vt[64][264];   // [n_local][c]
  f32x4 acc[4][4];
#pragma unroll
  for (int i = 0; i < 4; i++)
#pragma unroll
    for (int j = 0; j < 4; j++) acc[i][j] = {0.f, 0.f, 0.f, 0.f};
#pragma unroll 1
  for (int ks = 0; ks < 8; ks++) {
    short8 bfrag[4];
#pragma unroll
    for (int ns = 0; ns < 4; ns++)
      bfrag[ns] = *(const short8*)(Xf + ((((size_t)b * 256 + nblk * 4 + ns) * 8 + ks) * 64 + lane) * 8);
#pragma unroll
    for (int os = 0; os < 4; os++) {
      short8 af = *(const short8*)(Wvf + ((((size_t)(4 * w + os)) * 8 + ks) * 64 + lane) * 8);
#pragma unroll
      for (int ns = 0; ns < 4; ns++)
        acc[os][ns] = __builtin_amdgcn_mfma_f32_16x16x32_bf16(af, bfrag[ns], acc[os][ns], 0, 0, 0);
    }
  }
#pragma unroll
  for (int os = 0; os < 4; os++) {
    int c0 = w * 64 + os * 16 + lg * 4;
    float b0 = bv[c0], b1 = bv[c0 + 1], b2 = bv[c0 + 2], b3 = bv[c0 + 3];
#pragma unroll
    for (int ns = 0; ns < 4; ns++) {
      int2 pk;
      pk.x = cvtpk(acc[os][ns][0] + b0, acc[os][ns][1] + b1);
      pk.y = cvtpk(acc[os][ns][2] + b2, acc[os][ns][3] + b3);
      *(int2*)(&Vt[ns * 16 + lr][c0]) = pk;
    }
  }
  __syncthreads();
#pragma unroll
  for (int rr = 0; rr < 8; rr++) {
    int run = rr * 256 + threadIdx.x;
    int ksl = run >> 10, ctile = (run >> 6) & 15, ln = run & 63;
    short8 o;
#pragma unroll
    for (int j = 0; j < 8; j++)
      o[j] = Vt[ksl * 32 + ((ln >> 4) & 3) * 8 + j][ctile * 16 + (ln & 15)];
    size_t off = ((((size_t)b * 128 + 2 * nblk + ksl) * 16 + ctile) * 64 + ln) * 8;
    *(short8*)(Vf + off) = o;
  }
}

// K3: inv_rse[b][n] = 1/sum_m exp2(e). Frag loads, 1-deep prefetch, no LDS.
__global__ __launch_bounds__(256) void k3_rse(const short* __restrict__ Qf,
    const short* __restrict__ Kf, float* __restrict__ inv_rse) {
  int bid = blockIdx.x;
  int b = bid & 7, n0 = (bid >> 3) * 64;
  int lane = threadIdx.x & 63, w = threadIdx.x >> 6;
  int lg = lane >> 4;
  const short* Qb = Qf + (size_t)b * 256 * 2 * 512;
  const short* Kb = Kf + (size_t)b * 256 * 2 * 512;
  short8 qf[2];
#pragma unroll
  for (int ks = 0; ks < 2; ks++)
    qf[ks] = *(const short8*)(Qb + ((((size_t)(n0 >> 4) + w) * 2 + ks) * 64 + lane) * 8);
  short8 kc[4][2], kn[4][2];
#pragma unroll
  for (int ms = 0; ms < 4; ms++)
#pragma unroll
    for (int ks = 0; ks < 2; ks++)
      kc[ms][ks] = *(const short8*)(Kb + ((((size_t)ms) * 2 + ks) * 64 + lane) * 8);
  float rs[4] = {0.f, 0.f, 0.f, 0.f};
#pragma unroll 1
  for (int it = 0; it < 64; ++it) {
    int itn = (it < 63) ? it + 1 : it;
#pragma unroll
    for (int ms = 0; ms < 4; ms++)
#pragma unroll
      for (int ks = 0; ks < 2; ks++)
        kn[ms][ks] = *(const short8*)(Kb + ((((size_t)(itn * 4 + ms)) * 2 + ks) * 64 + lane) * 8);
#pragma unroll
    for (int ms = 0; ms < 4; ms++) {
      f32x4 e = {0.f, 0.f, 0.f, 0.f};
#pragma unroll
      for (int ks = 0; ks < 2; ks++)
        e = __builtin_amdgcn_mfma_f32_16x16x32_bf16(qf[ks], kc[ms][ks], e, 0, 0, 0);
#pragma unroll
      for (int r = 0; r < 4; r++) rs[r] += __builtin_amdgcn_exp2f(e[r]);
    }
#pragma unroll
    for (int ms = 0; ms < 4; ms++)
#pragma unroll
      for (int ks = 0; ks < 2; ks++) kc[ms][ks] = kn[ms][ks];
  }
#pragma unroll
  for (int off = 1; off < 16; off <<= 1)
#pragma unroll
    for (int r = 0; r < 4; r++) rs[r] += __shfl_xor(rs[r], off, 64);
  if ((lane & 15) == 0) {
#pragma unroll
    for (int r = 0; r < 4; r++)
      inv_rse[(size_t)b * N_ + n0 + w * 16 + lg * 4 + r] = 1.f / rs[r];
  }
}

// K4: fused energy->att->PV. 128 n per iter, frag-major global AND LDS layouts,
// raw s_barrier with lgkmcnt-only drain (V/Q prefetch stays in flight), setprio
// around PV MFMA cluster. Output Rf frag-major via LDS bounce.
__global__ __launch_bounds__(256, 2) void k4_att(const short* __restrict__ Qf,
    const short* __restrict__ Kf, const short* __restrict__ Vf,
    const float* __restrict__ inv_rse, short* __restrict__ Rf) {
  int bid = blockIdx.x;
  int b = bid & 7, mblk = bid >> 3, m0 = mblk * 64;
  int lane = threadIdx.x & 63, w = threadIdx.x >> 6;
  int lr = lane & 15, lg = lane >> 4;
  __shared__ __align__(16) short lds_raw[64 * 264];   // 33792 B; attf = 2 bufs x 8192 shorts
  __shared__ float cs_red[4][64];
  short* attf = lds_raw;              // attf[buf][frag 16][lane 64][8]
  const short* Qb = Qf + (size_t)b * 256 * 2 * 512;
  const short* Kb = Kf + (size_t)b * 256 * 2 * 512;
  const short* Vb = Vf + (size_t)b * 128 * 16 * 512;
  const float* irb = inv_rse + (size_t)b * N_;
  short8 kfrag[4][2];
#pragma unroll
  for (int ms = 0; ms < 4; ms++)
#pragma unroll
    for (int ks = 0; ks < 2; ks++)
      kfrag[ms][ks] = *(const short8*)(Kb + ((((size_t)(mblk * 4 + ms)) * 2 + ks) * 64 + lane) * 8);
  f32x4 P[4][4];
#pragma unroll
  for (int i = 0; i < 4; i++)
#pragma unroll
    for (int j = 0; j < 4; j++) P[i][j] = {0.f, 0.f, 0.f, 0.f};
  float csum[4] = {0.f, 0.f, 0.f, 0.f};
  short8 qf[2][2];
#pragma unroll
  for (int t = 0; t < 2; t++)
#pragma unroll
    for (int ks = 0; ks < 2; ks++)
      qf[t][ks] = *(const short8*)(Qb + ((((size_t)(t * 4 + w)) * 2 + ks) * 64 + lane) * 8);
  // att write target (constant per thread): frag kk = t*2 + (w>>1)
  int wln = lr + 16 * ((w & 1) * 2 + (lg >> 1));
  int wjo = (lg & 1) * 4;
  int buf = 0;
#pragma unroll 1
  for (int it2 = 0; it2 < 32; ++it2) {
    // irse first (so its wait doesn't drain later loads), then V, then QK, then Q-next
    f32x4 irv[2];
    irv[0] = *(const f32x4*)(irb + it2 * 128 + w * 16 + lg * 4);
    irv[1] = *(const f32x4*)(irb + it2 * 128 + 64 + w * 16 + lg * 4);
    short8 vf[4][4];
#pragma unroll
    for (int kk = 0; kk < 4; kk++)
#pragma unroll
      for (int cs = 0; cs < 4; cs++)
        vf[kk][cs] = *(const short8*)(Vb + ((((size_t)(it2 * 4 + kk)) * 16 + 4 * w + cs) * 64 + lane) * 8);
    f32x4 e[2][4];
#pragma unroll
    for (int t = 0; t < 2; t++)
#pragma unroll
      for (int ms = 0; ms < 4; ms++) {
        f32x4 a = {0.f, 0.f, 0.f, 0.f};
#pragma unroll
        for (int ks = 0; ks < 2; ks++)
          a = __builtin_amdgcn_mfma_f32_16x16x32_bf16(qf[t][ks], kfrag[ms][ks], a, 0, 0, 0);
        e[t][ms] = a;
      }
    int itn = (it2 < 31) ? it2 + 1 : it2;
    short8 qn[2][2];
#pragma unroll
    for (int t = 0; t < 2; t++)
#pragma unroll
      for (int ks = 0; ks < 2; ks++)
        qn[t][ks] = *(const short8*)(Qb + ((((size_t)(itn * 8 + t * 4 + w)) * 2 + ks) * 64 + lane) * 8);
#pragma unroll
    for (int t = 0; t < 2; t++) {
      int kk = t * 2 + (w >> 1);
#pragma unroll
      for (int ms = 0; ms < 4; ms++) {
        float a0 = __builtin_amdgcn_exp2f(e[t][ms][0]) * irv[t][0];
        float a1 = __builtin_amdgcn_exp2f(e[t][ms][1]) * irv[t][1];
        float a2 = __builtin_amdgcn_exp2f(e[t][ms][2]) * irv[t][2];
        float a3 = __builtin_amdgcn_exp2f(e[t][ms][3]) * irv[t][3];
        csum[ms] += (a0 + a1) + (a2 + a3);
        int2 pk;
        pk.x = cvtpk(a0, a1);
        pk.y = cvtpk(a2, a3);
        *(int2*)(attf + (size_t)buf * 8192 + (kk * 4 + ms) * 512 + wln * 8 + wjo) = pk;
      }
    }
    // raw barrier: only LDS needs draining; V/Q loads stay in flight across it
    asm volatile("s_waitcnt lgkmcnt(0)" ::: "memory");
    __builtin_amdgcn_s_barrier();
    __builtin_amdgcn_sched_barrier(0);
    __builtin_amdgcn_s_setprio(1);
#pragma unroll
    for (int kk = 0; kk < 4; kk++) {
      short8 bfr[4];
#pragma unroll
      for (int ms = 0; ms < 4; ms++)
        bfr[ms] = *(const short8*)(attf + (size_t)buf * 8192 + (kk * 4 + ms) * 512 + lane * 8);
#pragma unroll
      for (int cs = 0; cs < 4; cs++)
#pragma unroll
        for (int ms = 0; ms < 4; ms++)
          P[cs][ms] = __builtin_amdgcn_mfma_f32_16x16x32_bf16(vf[kk][cs], bfr[ms], P[cs][ms], 0, 0, 0);
    }
    __builtin_amdgcn_s_setprio(0);
#pragma unroll
    for (int t = 0; t < 2; t++)
#pragma unroll
      for (int ks = 0; ks < 2; ks++) qf[t][ks] = qn[t][ks];
    buf ^= 1;
  }
  // column-sum reduce over n, then normalize
#pragma unroll
  for (int off = 16; off < 64; off <<= 1)
#pragma unroll
    for (int ms = 0; ms < 4; ms++) csum[ms] += __shfl_xor(csum[ms], off, 64);
  if (lg == 0) {
#pragma unroll
    for (int ms = 0; ms < 4; ms++) cs_red[w][ms * 16 + lr] = csum[ms];
  }
  __syncthreads();   // full drain: PV reads done -> lds_raw reusable as Rt
  float cinv[4];
#pragma unroll
  for (int ms = 0; ms < 4; ms++) {
    int m = ms * 16 + lr;
    cinv[ms] = 1.f / (1e-9f + cs_red[0][m] + cs_red[1][m] + cs_red[2][m] + cs_red[3][m]);
  }
  short* Rt = lds_raw;               // Rt[64][264]
#pragma unroll
  for (int cs = 0; cs < 4; cs++) {
    int c0 = w * 64 + cs * 16 + lg * 4;
#pragma unroll
    for (int ms = 0; ms < 4; ms++) {
      int2 pk;
      pk.x = cvtpk(P[cs][ms][0] * cinv[ms], P[cs][ms][1] * cinv[ms]);
      pk.y = cvtpk(P[cs][ms][2] * cinv[ms], P[cs][ms][3] * cinv[ms]);
      *(int2*)(Rt + (ms * 16 + lr) * 264 + c0) = pk;
    }
  }
  __syncthreads();
#pragma unroll
  for (int rr = 0; rr < 8; rr++) {
    int run = rr * 256 + threadIdx.x;
    int mtl = run >> 9, ksc = (run >> 6) & 7, ln = run & 63;
    short8 o;
#pragma unroll
    for (int j = 0; j < 8; j++)
      o[j] = Rt[(mtl * 16 + (ln & 15)) * 264 + ksc * 32 + ((ln >> 4) & 3) * 8 + j];
    size_t off = ((((size_t)b * 256 + (m0 >> 4) + mtl) * 8 + ksc) * 64 + ln) * 8;
    *(short8*)(Rf + off) = o;
  }
}

// K5: out = x + relu(BN(W_t * x_r + b_t)); frag-major loads.
__global__ __launch_bounds__(256) void k5_out(const short* __restrict__ Wtf,
    const float* __restrict__ bt, const float* __restrict__ gamma,
    const float* __restrict__ beta, const float* __restrict__ mean,
    const float* __restrict__ var, const short* __restrict__ Rf,
    const float* __restrict__ x, float* __restrict__ out) {
  int bid = blockIdx.x;
  int b = bid & 7, m0 = (bid >> 3) * 64;
  int lane = threadIdx.x & 63, w = threadIdx.x >> 6;
  int lr = lane & 15, lg = lane >> 4;
  f32x4 acc[4][4];
#pragma unroll
  for (int i = 0; i < 4; i++)
#pragma unroll
    for (int j = 0; j < 4; j++) acc[i][j] = {0.f, 0.f, 0.f, 0.f};
#pragma unroll 1
  for (int ks = 0; ks < 8; ks++) {
    short8 bfr[4];
#pragma unroll
    for (int ms = 0; ms < 4; ms++)
      bfr[ms] = *(const short8*)(Rf + ((((size_t)b * 256 + (m0 >> 4) + ms) * 8 + ks) * 64 + lane) * 8);
#pragma unroll
    for (int os = 0; os < 4; os++) {
      short8 af = *(const short8*)(Wtf + ((((size_t)(4 * w + os)) * 8 + ks) * 64 + lane) * 8);
#pragma unroll
      for (int ms = 0; ms < 4; ms++)
        acc[os][ms] = __builtin_amdgcn_mfma_f32_16x16x32_bf16(af, bfr[ms], acc[os][ms], 0, 0, 0);
    }
  }
  const float* xb = x + (size_t)b * C_ * N_ + m0;
  float* ob = out + (size_t)b * C_ * N_ + m0;
#pragma unroll
  for (int os = 0; os < 4; os++)
#pragma unroll
    for (int r = 0; r < 4; r++) {
      int o = w * 64 + os * 16 + lg * 4 + r;
      float bb = bt[o];
      float iv = gamma[o] * rsqrtf(var[o] + 1e-5f);
      float mn = mean[o], be = beta[o];
#pragma unroll
      for (int ms = 0; ms < 4; ms++) {
        int m = ms * 16 + lr;
        float v = (acc[os][ms][r] + bb - mn) * iv + be;
        v = fmaxf(v, 0.f);
        ob[(size_t)o * N_ + m] = xb[(size_t)o * N_ + m] + v;
      }
    }
}

extern "C" void kernel_launch(void* const* d_in, const int* in_sizes, int n_in,
                              void* d_out, int out_size, void* d_ws, size_t ws_size,
                              hipStream_t stream) {
  const float* x     = (const float*)d_in[0];
  const float* Wqk   = (const float*)d_in[1];
  const float* Wk2c  = (const float*)d_in[2];
  const float* Wv    = (const float*)d_in[3];
  const float* bv    = (const float*)d_in[4];
  const float* Wt    = (const float*)d_in[5];
  const float* bt    = (const float*)d_in[6];
  const float* gamma = (const float*)d_in[7];
  const float* beta  = (const float*)d_in[8];
  const float* mean  = (const float*)d_in[9];
  const float* var   = (const float*)d_in[10];
  const int*   idx   = (const int*)d_in[11];
  float* out = (float*)d_out;

  char* ws = (char*)d_ws;
  size_t off = 0;
  auto alloc = [&](size_t bytes) -> void* {
    void* p = ws + off;
    off = (off + bytes + 255) & ~(size_t)255;
    return p;
  };
  short* Xf   = (short*)alloc((size_t)B_ * N_ * C_ * 2);
  short* Qf   = (short*)alloc((size_t)B_ * N_ * S_ * 2);
  short* Kf   = (short*)alloc((size_t)B_ * N_ * S_ * 2);
  short* Vf   = (short*)alloc((size_t)B_ * C_ * N_ * 2);
  float* irse = (float*)alloc((size_t)B_ * N_ * 4);
  short* Rf   = (short*)alloc((size_t)B_ * N_ * C_ * 2);
  short* Wvf  = (short*)alloc((size_t)C_ * C_ * 2);
  short* Wtf  = (short*)alloc((size_t)C_ * C_ * 2);

  kw_conv<<<dim3(64), 256, 0, stream>>>(Wv, Wt, Wvf, Wtf);
  k1_qk<<<dim3(512), dim3(64, 4), 0, stream>>>(x, Wqk, Wk2c, idx, Qf, Kf, Xf);
  k2_xv<<<dim3(512), 256, 0, stream>>>(Wvf, bv, Xf, Vf);
  k3_rse<<<dim3(512), 256, 0, stream>>>(Qf, Kf, irse);
  k4_att<<<dim3(512), 256, 0, stream>>>(Qf, Kf, Vf, irse, Rf);
  k5_out<<<dim3(512), 256, 0, stream>>>(Wtf, bt, gamma, beta, mean, var, Rf, x, out);
}